// Round 3
// baseline (875.962 us; speedup 1.0000x reference)
//
#include <hip/hip_runtime.h>
#include <stdint.h>

// ---------- types ----------
typedef __attribute__((ext_vector_type(4))) uint16_t u16x4;
typedef __attribute__((ext_vector_type(8))) uint16_t u16x8;
typedef __attribute__((ext_vector_type(8))) __bf16  bf16x8;
typedef __attribute__((ext_vector_type(4))) float   f32x4;

__device__ __forceinline__ uint16_t f2bf(float f) {
  uint32_t x = __float_as_uint(f);
  x += 0x7fffu + ((x >> 16) & 1u);   // RNE
  return (uint16_t)(x >> 16);
}
__device__ __forceinline__ f32x4 mfma32(bf16x8 a, bf16x8 b, f32x4 c) {
  return __builtin_amdgcn_mfma_f32_16x16x32_bf16(a, b, c, 0, 0, 0);
}
// async global->LDS, 16B/lane. LDS dest = wave-uniform base + lane*16.
__device__ __forceinline__ void gld16(const uint16_t* g, uint16_t* s) {
  __builtin_amdgcn_global_load_lds(
      (const __attribute__((address_space(1))) void*)g,
      (__attribute__((address_space(3))) void*)s, 16, 0, 0);
}

// Problem: B=2, frames=16, spatial=1024, hidden=1024, nh=16, hd=64.
// Inputs/outputs are FLOAT32 (per reference). Internals bf16 for MFMA.
// n = b*1024+sp in [0,2048), chunked over n to fit ws_size.

// ---------- 0) weights f32 -> bf16 (w_qkv 3072x1024 then w_out 1024x1024) ----------
__global__ __launch_bounds__(256)
void conv_w(const float* __restrict__ wq, const float* __restrict__ wo,
            uint16_t* __restrict__ dst) {
  int i = blockIdx.x * 256 + threadIdx.x;        // vec4 idx, 1048576 total
  float4 v = (i < 786432) ? ((const float4*)wq)[i]
                          : ((const float4*)wo)[i - 786432];
  u16x4 o;
  o[0] = f2bf(v.x); o[1] = f2bf(v.y); o[2] = f2bf(v.z); o[3] = f2bf(v.w);
  ((u16x4*)dst)[i] = o;
}

// ---------- 1) LayerNorm (f32 in) + gather into xt_chunk[nl*16+t][d] (bf16) ----------
__global__ __launch_bounds__(256)
void ln_chunk(const float* __restrict__ x, const float* __restrict__ gw,
              const float* __restrict__ bw, uint16_t* __restrict__ xt, int c0) {
  const int wv = threadIdx.x >> 6, lane = threadIdx.x & 63;
  const int r = blockIdx.x * 4 + wv;        // local xt row: nl*16 + t
  const int nl = r >> 4, t = r & 15;
  const int n = c0 + nl, b = n >> 10, sp = n & 1023;
  const float* xr = x + ((size_t)b * 16384 + (size_t)t * 1024 + sp) * 1024;
  float4 v[4];
#pragma unroll
  for (int c = 0; c < 4; ++c) v[c] = ((const float4*)xr)[c * 64 + lane];
  float s = 0.f, ss = 0.f;
#pragma unroll
  for (int c = 0; c < 4; ++c) {
    s  += v[c].x + v[c].y + v[c].z + v[c].w;
    ss += v[c].x * v[c].x + v[c].y * v[c].y + v[c].z * v[c].z + v[c].w * v[c].w;
  }
#pragma unroll
  for (int o = 32; o > 0; o >>= 1) { s += __shfl_xor(s, o); ss += __shfl_xor(ss, o); }
  const float mu = s * (1.f / 1024.f);
  const float var = ss * (1.f / 1024.f) - mu * mu;
  const float rs = rsqrtf(var + 1e-5f);
  uint16_t* orow = xt + (size_t)r * 1024;
#pragma unroll
  for (int c = 0; c < 4; ++c) {
    float4 g = ((const float4*)gw)[c * 64 + lane];
    float4 be = ((const float4*)bw)[c * 64 + lane];
    u16x4 o;
    o[0] = f2bf((v[c].x - mu) * rs * g.x + be.x);
    o[1] = f2bf((v[c].y - mu) * rs * g.y + be.y);
    o[2] = f2bf((v[c].z - mu) * rs * g.z + be.z);
    o[3] = f2bf((v[c].w - mu) * rs * g.w + be.w);
    ((u16x4*)orow)[c * 64 + lane] = o;
  }
}

// ---------- 2&4) C = A * B^T GEMM (bf16 in), K=1024, global_load_lds staging ----------
// BM=BN=128, BK=64, 4 waves (2x2 of 64x64), 16x16x32 MFMA.
// T3-min 2-phase schedule: double-buffered LDS, prefetch tile t+1 issued
// BEFORE computing tile t, ONE __syncthreads() per K-step (its implicit
// vmcnt(0) drain overlaps with the ds_read+MFMA phase).
// LDS layout (both sides): LDS[row][c] = global[row][c ^ (row&7)] (chunk XOR
// swizzle), applied on the GLOBAL source address since global_load_lds
// writes linearly.  Read side (kchunk XOR) unchanged.
// EPI==1: qkv epilogue (RoPE on q,k; q scaled 0.125) -> C0=q,C1=k,C2=v (bf16)
// as [nl][h][t][d].  EPI==0: store FLOAT32 to F0, local row l -> t=l>>lgc,
// nl=l&(chunkN-1), grow = b*16384 + t*1024 + sp.
template <int EPI>
__global__ __launch_bounds__(256)
void gemm_bt(const uint16_t* __restrict__ A, const uint16_t* __restrict__ B,
             uint16_t* __restrict__ C0, uint16_t* __restrict__ C1,
             uint16_t* __restrict__ C2, float* __restrict__ F0, int c0, int lgc) {
  __shared__ __align__(16) uint16_t As[2][8192];   // 128 rows x 64, chunk-swizzled
  __shared__ __align__(16) uint16_t Bs[2][8192];
  const int tid = threadIdx.x, lane = tid & 63, w = tid >> 6;
  const int bn = blockIdx.x, bm = blockIdx.y;
  const int srow = lane >> 3;               // 0..7
  const int schunk = (lane & 7) ^ srow;     // pre-swizzled global source chunk
  const uint16_t* ga = A + (size_t)(bm * 128 + w * 32 + srow) * 1024 + schunk * 8;
  const uint16_t* gb = B + (size_t)(bn * 128 + w * 32 + srow) * 1024 + schunk * 8;
  const int sOff = w * 2048;                // wave-uniform LDS base (32 rows x 64)
  const int wm = w >> 1, wn = w & 1;
  const int fr = lane & 15, quad = lane >> 4;
  f32x4 acc[4][4];
#pragma unroll
  for (int i = 0; i < 4; ++i)
#pragma unroll
    for (int j = 0; j < 4; ++j) acc[i][j] = (f32x4){0.f, 0.f, 0.f, 0.f};

  // prologue: stage K-tile 0 into buffer 0
#pragma unroll
  for (int i = 0; i < 4; ++i) {
    gld16(ga + (size_t)i * 8192, As[0] + sOff + i * 512);
    gld16(gb + (size_t)i * 8192, Bs[0] + sOff + i * 512);
  }
  ga += 64; gb += 64;
  __syncthreads();                   // drains vmcnt(0): tile 0 resident

#pragma unroll 2
  for (int kt = 0; kt < 16; ++kt) {
    const int cur = kt & 1;
    if (kt < 15) {                   // issue prefetch of tile kt+1 FIRST
#pragma unroll
      for (int i = 0; i < 4; ++i) {
        gld16(ga + (size_t)i * 8192, As[cur ^ 1] + sOff + i * 512);
        gld16(gb + (size_t)i * 8192, Bs[cur ^ 1] + sOff + i * 512);
      }
      ga += 64; gb += 64;
    }
    // compute tile kt from buffer cur (hides prefetch latency)
#pragma unroll
    for (int ko = 0; ko < 2; ++ko) {
      const int kchunk = ((ko * 4 + quad) ^ (fr & 7)) * 8;
      bf16x8 a[4], b[4];
#pragma unroll
      for (int tm = 0; tm < 4; ++tm)
        a[tm] = *(const bf16x8*)&As[cur][(wm * 64 + tm * 16 + fr) * 64 + kchunk];
#pragma unroll
      for (int tn = 0; tn < 4; ++tn)
        b[tn] = *(const bf16x8*)&Bs[cur][(wn * 64 + tn * 16 + fr) * 64 + kchunk];
#pragma unroll
      for (int tm = 0; tm < 4; ++tm)
#pragma unroll
        for (int tn = 0; tn < 4; ++tn)
          acc[tm][tn] = mfma32(a[tm], b[tn], acc[tm][tn]);
    }
    // one barrier per K-step: publishes buf[cur^1] writes AND protects
    // buf[cur] from being overwritten by the t+2 prefetch.
    __syncthreads();
  }

  // C/D layout: row = quad*4+r, col = fr (verified m89/m91)
  if (EPI == 0) {
#pragma unroll
    for (int tm = 0; tm < 4; ++tm) {
#pragma unroll
      for (int tn = 0; tn < 4; ++tn) {
        int colg = bn * 128 + wn * 64 + tn * 16 + fr;
#pragma unroll
        for (int r = 0; r < 4; ++r) {
          int l = bm * 128 + wm * 64 + tm * 16 + quad * 4 + r;   // local row
          int t = l >> lgc, nl = l & ((1 << lgc) - 1);
          int n = c0 + nl, b = n >> 10, sp = n & 1023;
          size_t grow = (size_t)b * 16384 + (size_t)t * 1024 + sp;
          F0[grow * 1024 + colg] = acc[tm][tn][r];
        }
      }
    }
  } else {
    // RoPE tables built AFTER the K-loop, reusing As/Bs LDS.
    // (loop's final barrier already fenced the last LDS reads)
    float* cosT = (float*)As;    // [t][i], t<16, i<32 (512 floats = 2KB)
    float* sinT = (float*)Bs;
    for (int idx = tid; idx < 512; idx += 256) {
      int t = idx >> 5, i = idx & 31;
      float ang = (float)t * expf(-(float)i * 0.28782313662425574f); // 10000^(-i/32)
      cosT[idx] = cosf(ang);
      sinT[idx] = sinf(ang);
    }
    __syncthreads();
    // wave's 64-col span = one (which, head); local row m = nl*16 + t
    const int e0 = bn * 128 + wn * 64;
    const int which = e0 >> 10;
    const int h = (e0 >> 6) & 15;
    const int n_base = bm * 8 + wm * 4;    // local nl base
    if (which == 2) {                      // v: plain scatter to [nl][h][t][d]
#pragma unroll
      for (int tm = 0; tm < 4; ++tm) {
        size_t base = ((size_t)(n_base + tm) * 16 + h) * 1024 + (size_t)(quad * 4) * 64;
#pragma unroll
        for (int tn = 0; tn < 4; ++tn) {
          int d = tn * 16 + fr;
#pragma unroll
          for (int r = 0; r < 4; ++r)
            C2[base + (size_t)r * 64 + d] = f2bf(acc[tm][tn][r]);
        }
      }
    } else {                               // q,k: RoPE (d pairs with d+32)
      uint16_t* dst = (which == 0) ? C0 : C1;
      const float sc = (which == 0) ? 0.125f : 1.0f;  // fold hd^-0.5 into q
#pragma unroll
      for (int tm = 0; tm < 4; ++tm) {
        size_t base0 = ((size_t)(n_base + tm) * 16 + h) * 1024;
#pragma unroll
        for (int tn2 = 0; tn2 < 2; ++tn2) {
          int d1 = tn2 * 16 + fr;          // < 32; pairs with tile tn2+2
#pragma unroll
          for (int r = 0; r < 4; ++r) {
            int t = quad * 4 + r;
            float c = cosT[t * 32 + d1], s = sinT[t * 32 + d1];
            float x1 = acc[tm][tn2][r], x2 = acc[tm][tn2 + 2][r];
            dst[base0 + (size_t)t * 64 + d1]      = f2bf((x1 * c - x2 * s) * sc);
            dst[base0 + (size_t)t * 64 + d1 + 32] = f2bf((x2 * c + x1 * s) * sc);
          }
        }
      }
    }
  }
}

// ---------- 3) causal attention over T=16, one wave per local (nl,h) ----------
// writes o_chunk[t*chunkN + nl][h*64+d] (bf16; reuses the dead xt buffer)
__global__ __launch_bounds__(256)
void attn_chunk(const uint16_t* __restrict__ q, const uint16_t* __restrict__ k,
                const uint16_t* __restrict__ v, uint16_t* __restrict__ out,
                int chunkN) {
  __shared__ float sPT[4][16][17];
  const int wv = threadIdx.x >> 6, lane = threadIdx.x & 63;
  const int pair = blockIdx.x * 4 + wv;     // nl*16 + h
  const int nl = pair >> 4, h = pair & 15;
  const uint16_t* qb = q + (size_t)pair * 1024;   // [t][d] 16x64
  const uint16_t* kb = k + (size_t)pair * 1024;
  const uint16_t* vb = v + (size_t)pair * 1024;
  const int col = lane & 15, quad = lane >> 4;
  const int ro = col * 64 + quad * 8;
  // S^T = K * Q^T : A[m=tk][kd=d] from K rows, B[n=tq][kd=d] from Q rows
  bf16x8 ka0 = *(const bf16x8*)(kb + ro);
  bf16x8 ka1 = *(const bf16x8*)(kb + ro + 32);
  bf16x8 qa0 = *(const bf16x8*)(qb + ro);
  bf16x8 qa1 = *(const bf16x8*)(qb + ro + 32);
  f32x4 s4 = (f32x4){0.f, 0.f, 0.f, 0.f};
  s4 = mfma32(ka0, qa0, s4);
  s4 = mfma32(ka1, qa1, s4);
  // lane holds S^T[tk=quad*4+r][tq=col]; softmax over tk
  float p[4];
  float mx = -3.0e38f;
#pragma unroll
  for (int r = 0; r < 4; ++r) {
    int tk = quad * 4 + r;
    p[r] = (tk <= col) ? s4[r] : -3.0e38f;  // causal mask (finite, no inf-inf)
    mx = fmaxf(mx, p[r]);
  }
  mx = fmaxf(mx, __shfl_xor(mx, 16));
  mx = fmaxf(mx, __shfl_xor(mx, 32));
  float sum = 0.f;
#pragma unroll
  for (int r = 0; r < 4; ++r) {
    p[r] = (p[r] <= -1.0e38f) ? 0.f : expf(p[r] - mx);
    sum += p[r];
  }
  sum += __shfl_xor(sum, 16);
  sum += __shfl_xor(sum, 32);
  const float inv = 1.f / sum;
  // LDS round-trip: P^T(C-layout) -> P(A-layout)
#pragma unroll
  for (int r = 0; r < 4; ++r) sPT[wv][quad * 4 + r][col] = p[r] * inv;
  __syncthreads();
  bf16x8 pa;   // A[m=tq=col][kd=tk=quad*8+j], K-pad quads zeroed
#pragma unroll
  for (int j = 0; j < 8; ++j) {
    float pv = (quad < 2) ? sPT[wv][(quad * 8 + j) & 15][col] : 0.f;
    pa[j] = (__bf16)pv;
  }
  const __bf16* vbf = (const __bf16*)vb;
#pragma unroll
  for (int dt = 0; dt < 4; ++dt) {
    bf16x8 bv;    // B-frag[n=dt*16+col][kd=tk=quad*8+j] = V[tk][d]; pad zeroed
#pragma unroll
    for (int j = 0; j < 8; ++j) {
      int tk = (quad * 8 + j) & 15;
      __bf16 val = vbf[tk * 64 + dt * 16 + col];
      bv[j] = (quad < 2) ? val : (__bf16)0.f;
    }
    f32x4 o = (f32x4){0.f, 0.f, 0.f, 0.f};
    o = mfma32(pa, bv, o);
#pragma unroll
    for (int r = 0; r < 4; ++r) {    // o_chunk[t*chunkN+nl][h*64+d]
      int t = quad * 4 + r;
      out[((size_t)t * chunkN + nl) * 1024 + h * 64 + dt * 16 + col] = f2bf(o[r]);
    }
  }
}

// ---------- launch ----------
extern "C" void kernel_launch(void* const* d_in, const int* in_sizes, int n_in,
                              void* d_out, int out_size, void* d_ws, size_t ws_size,
                              hipStream_t stream) {
  const float* x     = (const float*)d_in[0];
  const float* w_qkv = (const float*)d_in[1];
  const float* w_out = (const float*)d_in[2];
  const float* gamma = (const float*)d_in[3];
  const float* beta  = (const float*)d_in[4];
  float* out = (float*)d_out;

  // ws: [w_qkv_bf 3145728 | w_out_bf 1048576] + per-chunk xt/q/k/v
  uint16_t* wqb = (uint16_t*)d_ws;
  uint16_t* wob = wqb + 3145728;
  uint16_t* base = wob + 1048576;
  const size_t wbytes = 4194304ull * 2;
  size_t avail = (ws_size > wbytes) ? ws_size - wbytes : 0;
  size_t chunkN = 2048;
  while (chunkN > 8 && chunkN * 131072ull > avail) chunkN >>= 1;
  int lgc = 31 - __builtin_clz((unsigned)chunkN);
  const int nch = (int)(2048 / chunkN);
  const size_t seg = chunkN * 16384;   // bf16 elems per buffer
  uint16_t* xt = base;                 // xt, later reused as attn output
  uint16_t* qb = xt + seg;
  uint16_t* kb = qb + seg;
  uint16_t* vb = kb + seg;

  conv_w<<<dim3(4096), dim3(256), 0, stream>>>(w_qkv, w_out, wqb);
  for (int c = 0; c < nch; ++c) {
    const int c0 = c * (int)chunkN;
    ln_chunk<<<dim3((uint32_t)chunkN * 4), dim3(256), 0, stream>>>(
        x, gamma, beta, xt, c0);
    gemm_bt<1><<<dim3(24, (uint32_t)chunkN / 8), dim3(256), 0, stream>>>(
        xt, wqb, qb, kb, vb, nullptr, 0, 0);
    attn_chunk<<<dim3((uint32_t)chunkN * 4), dim3(256), 0, stream>>>(
        qb, kb, vb, xt, (int)chunkN);
    gemm_bt<0><<<dim3(8, (uint32_t)chunkN / 8), dim3(256), 0, stream>>>(
        xt, wob, nullptr, nullptr, nullptr, out, c0, lgc);
  }
}

// Round 4
// 823.139 us; speedup vs baseline: 1.0642x; 1.0642x over previous
//
#include <hip/hip_runtime.h>
#include <stdint.h>

// ---------- types ----------
typedef __attribute__((ext_vector_type(4))) uint16_t u16x4;
typedef __attribute__((ext_vector_type(8))) uint16_t u16x8;
typedef __attribute__((ext_vector_type(8))) __bf16  bf16x8;
typedef __attribute__((ext_vector_type(4))) float   f32x4;

__device__ __forceinline__ uint16_t f2bf(float f) {
  uint32_t x = __float_as_uint(f);
  x += 0x7fffu + ((x >> 16) & 1u);   // RNE
  return (uint16_t)(x >> 16);
}
__device__ __forceinline__ f32x4 mfma32(bf16x8 a, bf16x8 b, f32x4 c) {
  return __builtin_amdgcn_mfma_f32_16x16x32_bf16(a, b, c, 0, 0, 0);
}
// async global->LDS, 16B/lane. LDS dest = wave-uniform base + lane*16.
__device__ __forceinline__ void gld16(const uint16_t* g, uint16_t* s) {
  __builtin_amdgcn_global_load_lds(
      (const __attribute__((address_space(1))) void*)g,
      (__attribute__((address_space(3))) void*)s, 16, 0, 0);
}

// Problem: B=2, frames=16, spatial=1024, hidden=1024, nh=16, hd=64.
// Inputs/outputs are FLOAT32 (per reference). Internals bf16 for MFMA.
// n = b*1024+sp in [0,2048), chunked over n to fit ws_size.

// ---------- 0) weights f32 -> bf16 (w_qkv 3072x1024 then w_out 1024x1024) ----------
__global__ __launch_bounds__(256)
void conv_w(const float* __restrict__ wq, const float* __restrict__ wo,
            uint16_t* __restrict__ dst) {
  int i = blockIdx.x * 256 + threadIdx.x;        // vec4 idx, 1048576 total
  float4 v = (i < 786432) ? ((const float4*)wq)[i]
                          : ((const float4*)wo)[i - 786432];
  u16x4 o;
  o[0] = f2bf(v.x); o[1] = f2bf(v.y); o[2] = f2bf(v.z); o[3] = f2bf(v.w);
  ((u16x4*)dst)[i] = o;
}

// ---------- 1) LayerNorm (f32 in) + gather into xt_chunk[nl*16+t][d] (bf16) ----------
__global__ __launch_bounds__(256)
void ln_chunk(const float* __restrict__ x, const float* __restrict__ gw,
              const float* __restrict__ bw, uint16_t* __restrict__ xt, int c0) {
  const int wv = threadIdx.x >> 6, lane = threadIdx.x & 63;
  const int r = blockIdx.x * 4 + wv;        // local xt row: nl*16 + t
  const int nl = r >> 4, t = r & 15;
  const int n = c0 + nl, b = n >> 10, sp = n & 1023;
  const float* xr = x + ((size_t)b * 16384 + (size_t)t * 1024 + sp) * 1024;
  float4 v[4];
#pragma unroll
  for (int c = 0; c < 4; ++c) v[c] = ((const float4*)xr)[c * 64 + lane];
  float s = 0.f, ss = 0.f;
#pragma unroll
  for (int c = 0; c < 4; ++c) {
    s  += v[c].x + v[c].y + v[c].z + v[c].w;
    ss += v[c].x * v[c].x + v[c].y * v[c].y + v[c].z * v[c].z + v[c].w * v[c].w;
  }
#pragma unroll
  for (int o = 32; o > 0; o >>= 1) { s += __shfl_xor(s, o); ss += __shfl_xor(ss, o); }
  const float mu = s * (1.f / 1024.f);
  const float var = ss * (1.f / 1024.f) - mu * mu;
  const float rs = rsqrtf(var + 1e-5f);
  uint16_t* orow = xt + (size_t)r * 1024;
#pragma unroll
  for (int c = 0; c < 4; ++c) {
    float4 g = ((const float4*)gw)[c * 64 + lane];
    float4 be = ((const float4*)bw)[c * 64 + lane];
    u16x4 o;
    o[0] = f2bf((v[c].x - mu) * rs * g.x + be.x);
    o[1] = f2bf((v[c].y - mu) * rs * g.y + be.y);
    o[2] = f2bf((v[c].z - mu) * rs * g.z + be.z);
    o[3] = f2bf((v[c].w - mu) * rs * g.w + be.w);
    ((u16x4*)orow)[c * 64 + lane] = o;
  }
}

// ---------- 2&4) C = A * B^T GEMM (bf16 in), K=1024, global_load_lds staging ----------
// BM=BN=128, BK=64, 4 waves (2x2 of 64x64), 16x16x32 MFMA.
// Round-2 loop (best measured) + T1 bijective XCD swizzle: consecutive
// LOGICAL blocks (which share an A panel) are grouped onto one XCD so
// A-panel re-reads hit that XCD's L2 instead of refetching via L3/HBM.
// Both grids have nwg % 8 == 0 -> simple swizzle is bijective.
// LDS layout (both sides): LDS[row][c] = global[row][c ^ (row&7)] (chunk XOR
// swizzle), applied on the GLOBAL source address since global_load_lds
// writes linearly.  Read side (kchunk XOR) unchanged.
// EPI==1: qkv epilogue (RoPE on q,k; q scaled 0.125) -> C0=q,C1=k,C2=v (bf16)
// as [nl][h][t][d].  EPI==0: store FLOAT32 to F0, local row l -> t=l>>lgc,
// nl=l&(chunkN-1), grow = b*16384 + t*1024 + sp.
template <int EPI>
__global__ __launch_bounds__(256)
void gemm_bt(const uint16_t* __restrict__ A, const uint16_t* __restrict__ B,
             uint16_t* __restrict__ C0, uint16_t* __restrict__ C1,
             uint16_t* __restrict__ C2, float* __restrict__ F0, int c0, int lgc) {
  __shared__ __align__(16) uint16_t As[8192];   // 128 rows x 64, chunk-swizzled
  __shared__ __align__(16) uint16_t Bs[8192];
  const int tid = threadIdx.x, lane = tid & 63, w = tid >> 6;
  // T1: bijective XCD-aware remap of the linear block id.
  const int gx = gridDim.x;
  const int nwg = gx * gridDim.y;
  int lin = blockIdx.y * gx + blockIdx.x;
  lin = (lin & 7) * (nwg >> 3) + (lin >> 3);    // nwg % 8 == 0
  const int bn = lin % gx, bm = lin / gx;
  const int srow = lane >> 3;               // 0..7
  const int schunk = (lane & 7) ^ srow;     // pre-swizzled global source chunk
  const uint16_t* ga = A + (size_t)(bm * 128 + w * 32 + srow) * 1024 + schunk * 8;
  const uint16_t* gb = B + (size_t)(bn * 128 + w * 32 + srow) * 1024 + schunk * 8;
  uint16_t* sA = As + w * 2048;             // wave-uniform base (32 rows x 64)
  uint16_t* sB = Bs + w * 2048;
  const int wm = w >> 1, wn = w & 1;
  const int fr = lane & 15, quad = lane >> 4;
  f32x4 acc[4][4];
#pragma unroll
  for (int i = 0; i < 4; ++i)
#pragma unroll
    for (int j = 0; j < 4; ++j) acc[i][j] = (f32x4){0.f, 0.f, 0.f, 0.f};

  for (int kt = 0; kt < 16; ++kt) {
    __syncthreads();                 // prev iteration's LDS reads done
#pragma unroll
    for (int i = 0; i < 4; ++i) {    // 8 x global_load_lds_dwordx4 / wave
      gld16(ga + (size_t)i * 8192, sA + i * 512);
      gld16(gb + (size_t)i * 8192, sB + i * 512);
    }
    ga += 64; gb += 64;
    __syncthreads();                 // compiler drains vmcnt(0) before barrier
#pragma unroll
    for (int ko = 0; ko < 2; ++ko) {
      const int kchunk = ((ko * 4 + quad) ^ (fr & 7)) * 8;
      bf16x8 a[4], b[4];
#pragma unroll
      for (int tm = 0; tm < 4; ++tm)
        a[tm] = *(const bf16x8*)&As[(wm * 64 + tm * 16 + fr) * 64 + kchunk];
#pragma unroll
      for (int tn = 0; tn < 4; ++tn)
        b[tn] = *(const bf16x8*)&Bs[(wn * 64 + tn * 16 + fr) * 64 + kchunk];
#pragma unroll
      for (int tm = 0; tm < 4; ++tm)
#pragma unroll
        for (int tn = 0; tn < 4; ++tn)
          acc[tm][tn] = mfma32(a[tm], b[tn], acc[tm][tn]);
    }
  }

  // C/D layout: row = quad*4+r, col = fr (verified m89/m91)
  if (EPI == 0) {
#pragma unroll
    for (int tm = 0; tm < 4; ++tm) {
#pragma unroll
      for (int tn = 0; tn < 4; ++tn) {
        int colg = bn * 128 + wn * 64 + tn * 16 + fr;
#pragma unroll
        for (int r = 0; r < 4; ++r) {
          int l = bm * 128 + wm * 64 + tm * 16 + quad * 4 + r;   // local row
          int t = l >> lgc, nl = l & ((1 << lgc) - 1);
          int n = c0 + nl, b = n >> 10, sp = n & 1023;
          size_t grow = (size_t)b * 16384 + (size_t)t * 1024 + sp;
          F0[grow * 1024 + colg] = acc[tm][tn][r];
        }
      }
    }
  } else {
    // RoPE tables built AFTER the K-loop, reusing As/Bs LDS (saves 4KB ->
    // 32KB/block).
    float* cosT = (float*)As;    // [t][i], t<16, i<32 (512 floats = 2KB)
    float* sinT = (float*)Bs;
    __syncthreads();             // all waves done reading As/Bs
    for (int idx = tid; idx < 512; idx += 256) {
      int t = idx >> 5, i = idx & 31;
      float ang = (float)t * expf(-(float)i * 0.28782313662425574f); // 10000^(-i/32)
      cosT[idx] = cosf(ang);
      sinT[idx] = sinf(ang);
    }
    __syncthreads();
    // wave's 64-col span = one (which, head); local row m = nl*16 + t
    const int e0 = bn * 128 + wn * 64;
    const int which = e0 >> 10;
    const int h = (e0 >> 6) & 15;
    const int n_base = bm * 8 + wm * 4;    // local nl base
    if (which == 2) {                      // v: plain scatter to [nl][h][t][d]
#pragma unroll
      for (int tm = 0; tm < 4; ++tm) {
        size_t base = ((size_t)(n_base + tm) * 16 + h) * 1024 + (size_t)(quad * 4) * 64;
#pragma unroll
        for (int tn = 0; tn < 4; ++tn) {
          int d = tn * 16 + fr;
#pragma unroll
          for (int r = 0; r < 4; ++r)
            C2[base + (size_t)r * 64 + d] = f2bf(acc[tm][tn][r]);
        }
      }
    } else {                               // q,k: RoPE (d pairs with d+32)
      uint16_t* dst = (which == 0) ? C0 : C1;
      const float sc = (which == 0) ? 0.125f : 1.0f;  // fold hd^-0.5 into q
#pragma unroll
      for (int tm = 0; tm < 4; ++tm) {
        size_t base0 = ((size_t)(n_base + tm) * 16 + h) * 1024;
#pragma unroll
        for (int tn2 = 0; tn2 < 2; ++tn2) {
          int d1 = tn2 * 16 + fr;          // < 32; pairs with tile tn2+2
#pragma unroll
          for (int r = 0; r < 4; ++r) {
            int t = quad * 4 + r;
            float c = cosT[t * 32 + d1], s = sinT[t * 32 + d1];
            float x1 = acc[tm][tn2][r], x2 = acc[tm][tn2 + 2][r];
            dst[base0 + (size_t)t * 64 + d1]      = f2bf((x1 * c - x2 * s) * sc);
            dst[base0 + (size_t)t * 64 + d1 + 32] = f2bf((x2 * c + x1 * s) * sc);
          }
        }
      }
    }
  }
}

// ---------- 3) causal attention over T=16, one wave per local (nl,h) ----------
// writes o_chunk[t*chunkN + nl][h*64+d] (bf16; reuses the dead xt buffer)
__global__ __launch_bounds__(256)
void attn_chunk(const uint16_t* __restrict__ q, const uint16_t* __restrict__ k,
                const uint16_t* __restrict__ v, uint16_t* __restrict__ out,
                int chunkN) {
  __shared__ float sPT[4][16][17];
  const int wv = threadIdx.x >> 6, lane = threadIdx.x & 63;
  const int pair = blockIdx.x * 4 + wv;     // nl*16 + h
  const int nl = pair >> 4, h = pair & 15;
  const uint16_t* qb = q + (size_t)pair * 1024;   // [t][d] 16x64
  const uint16_t* kb = k + (size_t)pair * 1024;
  const uint16_t* vb = v + (size_t)pair * 1024;
  const int col = lane & 15, quad = lane >> 4;
  const int ro = col * 64 + quad * 8;
  // S^T = K * Q^T : A[m=tk][kd=d] from K rows, B[n=tq][kd=d] from Q rows
  bf16x8 ka0 = *(const bf16x8*)(kb + ro);
  bf16x8 ka1 = *(const bf16x8*)(kb + ro + 32);
  bf16x8 qa0 = *(const bf16x8*)(qb + ro);
  bf16x8 qa1 = *(const bf16x8*)(qb + ro + 32);
  f32x4 s4 = (f32x4){0.f, 0.f, 0.f, 0.f};
  s4 = mfma32(ka0, qa0, s4);
  s4 = mfma32(ka1, qa1, s4);
  // lane holds S^T[tk=quad*4+r][tq=col]; softmax over tk
  float p[4];
  float mx = -3.0e38f;
#pragma unroll
  for (int r = 0; r < 4; ++r) {
    int tk = quad * 4 + r;
    p[r] = (tk <= col) ? s4[r] : -3.0e38f;  // causal mask (finite, no inf-inf)
    mx = fmaxf(mx, p[r]);
  }
  mx = fmaxf(mx, __shfl_xor(mx, 16));
  mx = fmaxf(mx, __shfl_xor(mx, 32));
  float sum = 0.f;
#pragma unroll
  for (int r = 0; r < 4; ++r) {
    p[r] = (p[r] <= -1.0e38f) ? 0.f : expf(p[r] - mx);
    sum += p[r];
  }
  sum += __shfl_xor(sum, 16);
  sum += __shfl_xor(sum, 32);
  const float inv = 1.f / sum;
  // LDS round-trip: P^T(C-layout) -> P(A-layout)
#pragma unroll
  for (int r = 0; r < 4; ++r) sPT[wv][quad * 4 + r][col] = p[r] * inv;
  __syncthreads();
  bf16x8 pa;   // A[m=tq=col][kd=tk=quad*8+j], K-pad quads zeroed
#pragma unroll
  for (int j = 0; j < 8; ++j) {
    float pv = (quad < 2) ? sPT[wv][(quad * 8 + j) & 15][col] : 0.f;
    pa[j] = (__bf16)pv;
  }
  const __bf16* vbf = (const __bf16*)vb;
#pragma unroll
  for (int dt = 0; dt < 4; ++dt) {
    bf16x8 bv;    // B-frag[n=dt*16+col][kd=tk=quad*8+j] = V[tk][d]; pad zeroed
#pragma unroll
    for (int j = 0; j < 8; ++j) {
      int tk = (quad * 8 + j) & 15;
      __bf16 val = vbf[tk * 64 + dt * 16 + col];
      bv[j] = (quad < 2) ? val : (__bf16)0.f;
    }
    f32x4 o = (f32x4){0.f, 0.f, 0.f, 0.f};
    o = mfma32(pa, bv, o);
#pragma unroll
    for (int r = 0; r < 4; ++r) {    // o_chunk[t*chunkN+nl][h*64+d]
      int t = quad * 4 + r;
      out[((size_t)t * chunkN + nl) * 1024 + h * 64 + dt * 16 + col] = f2bf(o[r]);
    }
  }
}

// ---------- launch ----------
extern "C" void kernel_launch(void* const* d_in, const int* in_sizes, int n_in,
                              void* d_out, int out_size, void* d_ws, size_t ws_size,
                              hipStream_t stream) {
  const float* x     = (const float*)d_in[0];
  const float* w_qkv = (const float*)d_in[1];
  const float* w_out = (const float*)d_in[2];
  const float* gamma = (const float*)d_in[3];
  const float* beta  = (const float*)d_in[4];
  float* out = (float*)d_out;

  // ws: [w_qkv_bf 3145728 | w_out_bf 1048576] + per-chunk xt/q/k/v
  uint16_t* wqb = (uint16_t*)d_ws;
  uint16_t* wob = wqb + 3145728;
  uint16_t* base = wob + 1048576;
  const size_t wbytes = 4194304ull * 2;
  size_t avail = (ws_size > wbytes) ? ws_size - wbytes : 0;
  size_t chunkN = 2048;
  while (chunkN > 8 && chunkN * 131072ull > avail) chunkN >>= 1;
  int lgc = 31 - __builtin_clz((unsigned)chunkN);
  const int nch = (int)(2048 / chunkN);
  const size_t seg = chunkN * 16384;   // bf16 elems per buffer
  uint16_t* xt = base;                 // xt, later reused as attn output
  uint16_t* qb = xt + seg;
  uint16_t* kb = qb + seg;
  uint16_t* vb = kb + seg;

  conv_w<<<dim3(4096), dim3(256), 0, stream>>>(w_qkv, w_out, wqb);
  for (int c = 0; c < nch; ++c) {
    const int c0 = c * (int)chunkN;
    ln_chunk<<<dim3((uint32_t)chunkN * 4), dim3(256), 0, stream>>>(
        x, gamma, beta, xt, c0);
    gemm_bt<1><<<dim3(24, (uint32_t)chunkN / 8), dim3(256), 0, stream>>>(
        xt, wqb, qb, kb, vb, nullptr, 0, 0);
    attn_chunk<<<dim3((uint32_t)chunkN * 4), dim3(256), 0, stream>>>(
        qb, kb, vb, xt, (int)chunkN);
    gemm_bt<0><<<dim3(8, (uint32_t)chunkN / 8), dim3(256), 0, stream>>>(
        xt, wob, nullptr, nullptr, nullptr, out, c0, lgc);
  }
}

// Round 5
// 628.369 us; speedup vs baseline: 1.3940x; 1.3100x over previous
//
#include <hip/hip_runtime.h>
#include <stdint.h>

// ---------- types ----------
typedef __attribute__((ext_vector_type(4))) uint16_t u16x4;
typedef __attribute__((ext_vector_type(8))) uint16_t u16x8;
typedef __attribute__((ext_vector_type(8))) __bf16  bf16x8;
typedef __attribute__((ext_vector_type(4))) float   f32x4;

__device__ __forceinline__ uint16_t f2bf(float f) {
  uint32_t x = __float_as_uint(f);
  x += 0x7fffu + ((x >> 16) & 1u);   // RNE
  return (uint16_t)(x >> 16);
}
__device__ __forceinline__ f32x4 mfma32(bf16x8 a, bf16x8 b, f32x4 c) {
  return __builtin_amdgcn_mfma_f32_16x16x32_bf16(a, b, c, 0, 0, 0);
}
// async global->LDS, 16B/lane. LDS dest = wave-uniform base + lane*16.
__device__ __forceinline__ void gld16(const uint16_t* g, uint16_t* s) {
  __builtin_amdgcn_global_load_lds(
      (const __attribute__((address_space(1))) void*)g,
      (__attribute__((address_space(3))) void*)s, 16, 0, 0);
}

// Problem: B=2, frames=16, spatial=1024, hidden=1024, nh=16, hd=64.
// Inputs/outputs are FLOAT32 (per reference). Internals bf16 for MFMA.
// n = b*1024+sp in [0,2048), chunked over n to fit ws_size.

// ---------- 0) weights f32 -> bf16 (w_qkv 3072x1024 then w_out 1024x1024) ----------
__global__ __launch_bounds__(256)
void conv_w(const float* __restrict__ wq, const float* __restrict__ wo,
            uint16_t* __restrict__ dst) {
  int i = blockIdx.x * 256 + threadIdx.x;        // vec4 idx, 1048576 total
  float4 v = (i < 786432) ? ((const float4*)wq)[i]
                          : ((const float4*)wo)[i - 786432];
  u16x4 o;
  o[0] = f2bf(v.x); o[1] = f2bf(v.y); o[2] = f2bf(v.z); o[3] = f2bf(v.w);
  ((u16x4*)dst)[i] = o;
}

// ---------- 1) LayerNorm (f32 in) + gather into xt_chunk[nl*16+t][d] (bf16) ----------
__global__ __launch_bounds__(256)
void ln_chunk(const float* __restrict__ x, const float* __restrict__ gw,
              const float* __restrict__ bw, uint16_t* __restrict__ xt, int c0) {
  const int wv = threadIdx.x >> 6, lane = threadIdx.x & 63;
  const int r = blockIdx.x * 4 + wv;        // local xt row: nl*16 + t
  const int nl = r >> 4, t = r & 15;
  const int n = c0 + nl, b = n >> 10, sp = n & 1023;
  const float* xr = x + ((size_t)b * 16384 + (size_t)t * 1024 + sp) * 1024;
  float4 v[4];
#pragma unroll
  for (int c = 0; c < 4; ++c) v[c] = ((const float4*)xr)[c * 64 + lane];
  float s = 0.f, ss = 0.f;
#pragma unroll
  for (int c = 0; c < 4; ++c) {
    s  += v[c].x + v[c].y + v[c].z + v[c].w;
    ss += v[c].x * v[c].x + v[c].y * v[c].y + v[c].z * v[c].z + v[c].w * v[c].w;
  }
#pragma unroll
  for (int o = 32; o > 0; o >>= 1) { s += __shfl_xor(s, o); ss += __shfl_xor(ss, o); }
  const float mu = s * (1.f / 1024.f);
  const float var = ss * (1.f / 1024.f) - mu * mu;
  const float rs = rsqrtf(var + 1e-5f);
  uint16_t* orow = xt + (size_t)r * 1024;
#pragma unroll
  for (int c = 0; c < 4; ++c) {
    float4 g = ((const float4*)gw)[c * 64 + lane];
    float4 be = ((const float4*)bw)[c * 64 + lane];
    u16x4 o;
    o[0] = f2bf((v[c].x - mu) * rs * g.x + be.x);
    o[1] = f2bf((v[c].y - mu) * rs * g.y + be.y);
    o[2] = f2bf((v[c].z - mu) * rs * g.z + be.z);
    o[3] = f2bf((v[c].w - mu) * rs * g.w + be.w);
    ((u16x4*)orow)[c * 64 + lane] = o;
  }
}

// ---------- 2&4) C = A * B^T GEMM (bf16 in), K=1024 ----------
// BM=BN=128, BK=64, 4 waves (2x2 of 64x64), 16x16x32 MFMA.
// T3+T4 minimum pipeline: double-buffered LDS, prefetch of tile kt+1 issued
// BEFORE the wait, then COUNTED `s_waitcnt vmcnt(8)` (waits only tile kt's 8
// loads; kt+1's 8 stay in flight across the barrier) + RAW s_barrier (no
// vmcnt(0) drain -- Round-3's __syncthreads drained the prefetch at issue,
// which is why it was neutral).  sched_barrier(0) pins all ds_read uses
// before the end barrier so no read is in flight when the next prefetch
// overwrites the buffer.
// LDS layout (both sides): LDS[row][c] = global[row][c ^ (row&7)] (chunk XOR
// swizzle), applied on the GLOBAL source address since global_load_lds
// writes linearly.  Read side (kchunk XOR) unchanged.
// EPI==1: qkv epilogue (RoPE on q,k; q scaled 0.125) -> C0=q,C1=k,C2=v (bf16)
// as [nl][h][t][d].  EPI==0: store FLOAT32 to F0, local row l -> t=l>>lgc,
// nl=l&(chunkN-1), grow = b*16384 + t*1024 + sp.
template <int EPI>
__global__ __launch_bounds__(256)
void gemm_bt(const uint16_t* __restrict__ A, const uint16_t* __restrict__ B,
             uint16_t* __restrict__ C0, uint16_t* __restrict__ C1,
             uint16_t* __restrict__ C2, float* __restrict__ F0, int c0, int lgc) {
  __shared__ __align__(16) uint16_t As[2][8192];   // 128 rows x 64, chunk-swizzled
  __shared__ __align__(16) uint16_t Bs[2][8192];
  const int tid = threadIdx.x, lane = tid & 63, w = tid >> 6;
  const int bn = blockIdx.x, bm = blockIdx.y;
  const int srow = lane >> 3;               // 0..7
  const int schunk = (lane & 7) ^ srow;     // pre-swizzled global source chunk
  const uint16_t* ga = A + (size_t)(bm * 128 + w * 32 + srow) * 1024 + schunk * 8;
  const uint16_t* gb = B + (size_t)(bn * 128 + w * 32 + srow) * 1024 + schunk * 8;
  const int sOff = w * 2048;                // wave-uniform LDS base (32 rows x 64)
  const int wm = w >> 1, wn = w & 1;
  const int fr = lane & 15, quad = lane >> 4;
  f32x4 acc[4][4];
#pragma unroll
  for (int i = 0; i < 4; ++i)
#pragma unroll
    for (int j = 0; j < 4; ++j) acc[i][j] = (f32x4){0.f, 0.f, 0.f, 0.f};

  // per-tile compute from buffer `cur` (16 ds_read_b128 + 32 MFMA)
  auto compute = [&](int cur) {
#pragma unroll
    for (int ko = 0; ko < 2; ++ko) {
      const int kchunk = ((ko * 4 + quad) ^ (fr & 7)) * 8;
      bf16x8 a[4], b[4];
#pragma unroll
      for (int tm = 0; tm < 4; ++tm)
        a[tm] = *(const bf16x8*)&As[cur][(wm * 64 + tm * 16 + fr) * 64 + kchunk];
#pragma unroll
      for (int tn = 0; tn < 4; ++tn)
        b[tn] = *(const bf16x8*)&Bs[cur][(wn * 64 + tn * 16 + fr) * 64 + kchunk];
#pragma unroll
      for (int tm = 0; tm < 4; ++tm)
#pragma unroll
        for (int tn = 0; tn < 4; ++tn)
          acc[tm][tn] = mfma32(a[tm], b[tn], acc[tm][tn]);
    }
  };

  // prologue: stage K-tile 0 into buffer 0 (8 loads/wave)
#pragma unroll
  for (int i = 0; i < 4; ++i) {
    gld16(ga + (size_t)i * 8192, &As[0][sOff + i * 512]);
    gld16(gb + (size_t)i * 8192, &Bs[0][sOff + i * 512]);
  }
  ga += 64; gb += 64;

#pragma unroll 2
  for (int kt = 0; kt < 15; ++kt) {
    const int cur = kt & 1;
    // issue prefetch of tile kt+1 into the other buffer (8 loads in flight)
#pragma unroll
    for (int i = 0; i < 4; ++i) {
      gld16(ga + (size_t)i * 8192, &As[cur ^ 1][sOff + i * 512]);
      gld16(gb + (size_t)i * 8192, &Bs[cur ^ 1][sOff + i * 512]);
    }
    ga += 64; gb += 64;
    __builtin_amdgcn_sched_barrier(0);
    asm volatile("s_waitcnt vmcnt(8)" ::: "memory");  // tile kt resident; kt+1 in flight
    __builtin_amdgcn_sched_barrier(0);
    __builtin_amdgcn_s_barrier();                     // raw: no vmcnt drain
    __builtin_amdgcn_sched_barrier(0);
    compute(cur);
    __builtin_amdgcn_sched_barrier(0);
    __builtin_amdgcn_s_barrier();   // all reads of buf[cur] done before kt+2 overwrites
  }
  // epilogue: tile 15 (no prefetch behind it)
  __builtin_amdgcn_sched_barrier(0);
  asm volatile("s_waitcnt vmcnt(0)" ::: "memory");
  __builtin_amdgcn_sched_barrier(0);
  __builtin_amdgcn_s_barrier();
  __builtin_amdgcn_sched_barrier(0);
  compute(1);

  // C/D layout: row = quad*4+r, col = fr (verified m89/m91)
  if (EPI == 0) {
#pragma unroll
    for (int tm = 0; tm < 4; ++tm) {
#pragma unroll
      for (int tn = 0; tn < 4; ++tn) {
        int colg = bn * 128 + wn * 64 + tn * 16 + fr;
#pragma unroll
        for (int r = 0; r < 4; ++r) {
          int l = bm * 128 + wm * 64 + tm * 16 + quad * 4 + r;   // local row
          int t = l >> lgc, nl = l & ((1 << lgc) - 1);
          int n = c0 + nl, b = n >> 10, sp = n & 1023;
          size_t grow = (size_t)b * 16384 + (size_t)t * 1024 + sp;
          F0[grow * 1024 + colg] = acc[tm][tn][r];
        }
      }
    }
  } else {
    // RoPE tables built AFTER the K-loop, reusing As/Bs LDS.
    float* cosT = (float*)As;    // [t][i], t<16, i<32 (512 floats = 2KB)
    float* sinT = (float*)&Bs[0][0];
    __syncthreads();             // all waves done reading As/Bs (full drain ok, once)
    for (int idx = tid; idx < 512; idx += 256) {
      int t = idx >> 5, i = idx & 31;
      float ang = (float)t * expf(-(float)i * 0.28782313662425574f); // 10000^(-i/32)
      cosT[idx] = cosf(ang);
      sinT[idx] = sinf(ang);
    }
    __syncthreads();
    // wave's 64-col span = one (which, head); local row m = nl*16 + t
    const int e0 = bn * 128 + wn * 64;
    const int which = e0 >> 10;
    const int h = (e0 >> 6) & 15;
    const int n_base = bm * 8 + wm * 4;    // local nl base
    if (which == 2) {                      // v: plain scatter to [nl][h][t][d]
#pragma unroll
      for (int tm = 0; tm < 4; ++tm) {
        size_t base = ((size_t)(n_base + tm) * 16 + h) * 1024 + (size_t)(quad * 4) * 64;
#pragma unroll
        for (int tn = 0; tn < 4; ++tn) {
          int d = tn * 16 + fr;
#pragma unroll
          for (int r = 0; r < 4; ++r)
            C2[base + (size_t)r * 64 + d] = f2bf(acc[tm][tn][r]);
        }
      }
    } else {                               // q,k: RoPE (d pairs with d+32)
      uint16_t* dst = (which == 0) ? C0 : C1;
      const float sc = (which == 0) ? 0.125f : 1.0f;  // fold hd^-0.5 into q
#pragma unroll
      for (int tm = 0; tm < 4; ++tm) {
        size_t base0 = ((size_t)(n_base + tm) * 16 + h) * 1024;
#pragma unroll
        for (int tn2 = 0; tn2 < 2; ++tn2) {
          int d1 = tn2 * 16 + fr;          // < 32; pairs with tile tn2+2
#pragma unroll
          for (int r = 0; r < 4; ++r) {
            int t = quad * 4 + r;
            float c = cosT[t * 32 + d1], s = sinT[t * 32 + d1];
            float x1 = acc[tm][tn2][r], x2 = acc[tm][tn2 + 2][r];
            dst[base0 + (size_t)t * 64 + d1]      = f2bf((x1 * c - x2 * s) * sc);
            dst[base0 + (size_t)t * 64 + d1 + 32] = f2bf((x2 * c + x1 * s) * sc);
          }
        }
      }
    }
  }
}

// ---------- 3) causal attention over T=16, one wave per local (nl,h) ----------
// writes o_chunk[t*chunkN + nl][h*64+d] (bf16; reuses the dead xt buffer)
__global__ __launch_bounds__(256)
void attn_chunk(const uint16_t* __restrict__ q, const uint16_t* __restrict__ k,
                const uint16_t* __restrict__ v, uint16_t* __restrict__ out,
                int chunkN) {
  __shared__ float sPT[4][16][17];
  const int wv = threadIdx.x >> 6, lane = threadIdx.x & 63;
  const int pair = blockIdx.x * 4 + wv;     // nl*16 + h
  const int nl = pair >> 4, h = pair & 15;
  const uint16_t* qb = q + (size_t)pair * 1024;   // [t][d] 16x64
  const uint16_t* kb = k + (size_t)pair * 1024;
  const uint16_t* vb = v + (size_t)pair * 1024;
  const int col = lane & 15, quad = lane >> 4;
  const int ro = col * 64 + quad * 8;
  // S^T = K * Q^T : A[m=tk][kd=d] from K rows, B[n=tq][kd=d] from Q rows
  bf16x8 ka0 = *(const bf16x8*)(kb + ro);
  bf16x8 ka1 = *(const bf16x8*)(kb + ro + 32);
  bf16x8 qa0 = *(const bf16x8*)(qb + ro);
  bf16x8 qa1 = *(const bf16x8*)(qb + ro + 32);
  f32x4 s4 = (f32x4){0.f, 0.f, 0.f, 0.f};
  s4 = mfma32(ka0, qa0, s4);
  s4 = mfma32(ka1, qa1, s4);
  // lane holds S^T[tk=quad*4+r][tq=col]; softmax over tk
  float p[4];
  float mx = -3.0e38f;
#pragma unroll
  for (int r = 0; r < 4; ++r) {
    int tk = quad * 4 + r;
    p[r] = (tk <= col) ? s4[r] : -3.0e38f;  // causal mask (finite, no inf-inf)
    mx = fmaxf(mx, p[r]);
  }
  mx = fmaxf(mx, __shfl_xor(mx, 16));
  mx = fmaxf(mx, __shfl_xor(mx, 32));
  float sum = 0.f;
#pragma unroll
  for (int r = 0; r < 4; ++r) {
    p[r] = (p[r] <= -1.0e38f) ? 0.f : expf(p[r] - mx);
    sum += p[r];
  }
  sum += __shfl_xor(sum, 16);
  sum += __shfl_xor(sum, 32);
  const float inv = 1.f / sum;
  // LDS round-trip: P^T(C-layout) -> P(A-layout)
#pragma unroll
  for (int r = 0; r < 4; ++r) sPT[wv][quad * 4 + r][col] = p[r] * inv;
  __syncthreads();
  bf16x8 pa;   // A[m=tq=col][kd=tk=quad*8+j], K-pad quads zeroed
#pragma unroll
  for (int j = 0; j < 8; ++j) {
    float pv = (quad < 2) ? sPT[wv][(quad * 8 + j) & 15][col] : 0.f;
    pa[j] = (__bf16)pv;
  }
  const __bf16* vbf = (const __bf16*)vb;
#pragma unroll
  for (int dt = 0; dt < 4; ++dt) {
    bf16x8 bv;    // B-frag[n=dt*16+col][kd=tk=quad*8+j] = V[tk][d]; pad zeroed
#pragma unroll
    for (int j = 0; j < 8; ++j) {
      int tk = (quad * 8 + j) & 15;
      __bf16 val = vbf[tk * 64 + dt * 16 + col];
      bv[j] = (quad < 2) ? val : (__bf16)0.f;
    }
    f32x4 o = (f32x4){0.f, 0.f, 0.f, 0.f};
    o = mfma32(pa, bv, o);
#pragma unroll
    for (int r = 0; r < 4; ++r) {    // o_chunk[t*chunkN+nl][h*64+d]
      int t = quad * 4 + r;
      out[((size_t)t * chunkN + nl) * 1024 + h * 64 + dt * 16 + col] = f2bf(o[r]);
    }
  }
}

// ---------- launch ----------
extern "C" void kernel_launch(void* const* d_in, const int* in_sizes, int n_in,
                              void* d_out, int out_size, void* d_ws, size_t ws_size,
                              hipStream_t stream) {
  const float* x     = (const float*)d_in[0];
  const float* w_qkv = (const float*)d_in[1];
  const float* w_out = (const float*)d_in[2];
  const float* gamma = (const float*)d_in[3];
  const float* beta  = (const float*)d_in[4];
  float* out = (float*)d_out;

  // ws: [w_qkv_bf 3145728 | w_out_bf 1048576] + per-chunk xt/q/k/v
  uint16_t* wqb = (uint16_t*)d_ws;
  uint16_t* wob = wqb + 3145728;
  uint16_t* base = wob + 1048576;
  const size_t wbytes = 4194304ull * 2;
  size_t avail = (ws_size > wbytes) ? ws_size - wbytes : 0;
  size_t chunkN = 2048;
  while (chunkN > 8 && chunkN * 131072ull > avail) chunkN >>= 1;
  int lgc = 31 - __builtin_clz((unsigned)chunkN);
  const int nch = (int)(2048 / chunkN);
  const size_t seg = chunkN * 16384;   // bf16 elems per buffer
  uint16_t* xt = base;                 // xt, later reused as attn output
  uint16_t* qb = xt + seg;
  uint16_t* kb = qb + seg;
  uint16_t* vb = kb + seg;

  conv_w<<<dim3(4096), dim3(256), 0, stream>>>(w_qkv, w_out, wqb);
  for (int c = 0; c < nch; ++c) {
    const int c0 = c * (int)chunkN;
    ln_chunk<<<dim3((uint32_t)chunkN * 4), dim3(256), 0, stream>>>(
        x, gamma, beta, xt, c0);
    gemm_bt<1><<<dim3(24, (uint32_t)chunkN / 8), dim3(256), 0, stream>>>(
        xt, wqb, qb, kb, vb, nullptr, 0, 0);
    attn_chunk<<<dim3((uint32_t)chunkN * 4), dim3(256), 0, stream>>>(
        qb, kb, vb, xt, (int)chunkN);
    gemm_bt<0><<<dim3(8, (uint32_t)chunkN / 8), dim3(256), 0, stream>>>(
        xt, wob, nullptr, nullptr, nullptr, out, c0, lgc);
  }
}

// Round 6
// 627.768 us; speedup vs baseline: 1.3954x; 1.0010x over previous
//
#include <hip/hip_runtime.h>
#include <stdint.h>

// ---------- types ----------
typedef __attribute__((ext_vector_type(4))) uint16_t u16x4;
typedef __attribute__((ext_vector_type(8))) uint16_t u16x8;
typedef __attribute__((ext_vector_type(8))) __bf16  bf16x8;
typedef __attribute__((ext_vector_type(4))) float   f32x4;

__device__ __forceinline__ uint16_t f2bf(float f) {
  uint32_t x = __float_as_uint(f);
  x += 0x7fffu + ((x >> 16) & 1u);   // RNE
  return (uint16_t)(x >> 16);
}
__device__ __forceinline__ f32x4 mfma32(bf16x8 a, bf16x8 b, f32x4 c) {
  return __builtin_amdgcn_mfma_f32_16x16x32_bf16(a, b, c, 0, 0, 0);
}
// async global->LDS, 16B/lane. LDS dest = wave-uniform base + lane*16.
__device__ __forceinline__ void gld16(const uint16_t* g, uint16_t* s) {
  __builtin_amdgcn_global_load_lds(
      (const __attribute__((address_space(1))) void*)g,
      (__attribute__((address_space(3))) void*)s, 16, 0, 0);
}

// Problem: B=2, frames=16, spatial=1024, hidden=1024, nh=16, hd=64.
// Inputs/outputs are FLOAT32 (per reference). Internals bf16 for MFMA.
// n = b*1024+sp in [0,2048), chunked over n to fit ws_size.

// ---------- 0) weights f32 -> bf16 (w_qkv 3072x1024 then w_out 1024x1024) ----------
__global__ __launch_bounds__(256)
void conv_w(const float* __restrict__ wq, const float* __restrict__ wo,
            uint16_t* __restrict__ dst) {
  int i = blockIdx.x * 256 + threadIdx.x;        // vec4 idx, 1048576 total
  float4 v = (i < 786432) ? ((const float4*)wq)[i]
                          : ((const float4*)wo)[i - 786432];
  u16x4 o;
  o[0] = f2bf(v.x); o[1] = f2bf(v.y); o[2] = f2bf(v.z); o[3] = f2bf(v.w);
  ((u16x4*)dst)[i] = o;
}

// ---------- 1) LayerNorm (f32 in) + gather into xt_chunk[nl*16+t][d] (bf16) ----------
__global__ __launch_bounds__(256)
void ln_chunk(const float* __restrict__ x, const float* __restrict__ gw,
              const float* __restrict__ bw, uint16_t* __restrict__ xt, int c0) {
  const int wv = threadIdx.x >> 6, lane = threadIdx.x & 63;
  const int r = blockIdx.x * 4 + wv;        // local xt row: nl*16 + t
  const int nl = r >> 4, t = r & 15;
  const int n = c0 + nl, b = n >> 10, sp = n & 1023;
  const float* xr = x + ((size_t)b * 16384 + (size_t)t * 1024 + sp) * 1024;
  float4 v[4];
#pragma unroll
  for (int c = 0; c < 4; ++c) v[c] = ((const float4*)xr)[c * 64 + lane];
  float s = 0.f, ss = 0.f;
#pragma unroll
  for (int c = 0; c < 4; ++c) {
    s  += v[c].x + v[c].y + v[c].z + v[c].w;
    ss += v[c].x * v[c].x + v[c].y * v[c].y + v[c].z * v[c].z + v[c].w * v[c].w;
  }
#pragma unroll
  for (int o = 32; o > 0; o >>= 1) { s += __shfl_xor(s, o); ss += __shfl_xor(ss, o); }
  const float mu = s * (1.f / 1024.f);
  const float var = ss * (1.f / 1024.f) - mu * mu;
  const float rs = rsqrtf(var + 1e-5f);
  uint16_t* orow = xt + (size_t)r * 1024;
#pragma unroll
  for (int c = 0; c < 4; ++c) {
    float4 g = ((const float4*)gw)[c * 64 + lane];
    float4 be = ((const float4*)bw)[c * 64 + lane];
    u16x4 o;
    o[0] = f2bf((v[c].x - mu) * rs * g.x + be.x);
    o[1] = f2bf((v[c].y - mu) * rs * g.y + be.y);
    o[2] = f2bf((v[c].z - mu) * rs * g.z + be.z);
    o[3] = f2bf((v[c].w - mu) * rs * g.w + be.w);
    ((u16x4*)orow)[c * 64 + lane] = o;
  }
}

// ---------- 2&4) C = A * B^T GEMM (bf16 in), K=1024 ----------
// BM=BN=256, BK=64, 8 waves (2M x 4N of 128x64 wave-tiles), 512 threads,
// 16x16x32 MFMA.  128x64 wave-tile => 24 ds_read_b128 per 64 MFMA
// (0.375/MFMA): LDS-read cycles (4.5/mfma) < MFMA cycles (4.85/mfma), so
// the matrix pipe is the binding resource (at 64x64 it was LDS-read-bound).
// Sync structure UNCHANGED from the verified round-5 loop: double-buffered
// LDS, prefetch kt+1 issued first, counted `s_waitcnt vmcnt(8)` (each wave
// has 8 loads/tile), raw s_barrier (no drain), sched_barrier(0) fences.
// LDS = 2 dbuf x (256x64 A + 256x64 B) x 2B = 128 KB -> 1 block/CU,
// 8 waves/CU (same as round-5's 2x4-wave blocks).
// LDS layout (both sides): LDS[row][c] = global[row][c ^ (row&7)] (chunk XOR
// swizzle), applied on the GLOBAL source address since global_load_lds
// writes linearly.  Read rows are == fr (mod 8) so read-side kchunk XOR
// is unchanged.
// EPI==1: qkv epilogue (RoPE on q,k; q scaled 0.125) -> C0=q,C1=k,C2=v (bf16)
// as [nl][h][t][d].  EPI==0: store FLOAT32 to F0, local row l -> t=l>>lgc,
// nl=l&(chunkN-1), grow = b*16384 + t*1024 + sp.
template <int EPI>
__global__ __launch_bounds__(512)
void gemm_bt(const uint16_t* __restrict__ A, const uint16_t* __restrict__ B,
             uint16_t* __restrict__ C0, uint16_t* __restrict__ C1,
             uint16_t* __restrict__ C2, float* __restrict__ F0, int c0, int lgc) {
  __shared__ __align__(16) uint16_t As[2][16384];   // 256 rows x 64, chunk-swizzled
  __shared__ __align__(16) uint16_t Bs[2][16384];
  const int tid = threadIdx.x, lane = tid & 63, w = tid >> 6;   // w: 0..7
  const int bn = blockIdx.x, bm = blockIdx.y;
  const int srow = lane >> 3;               // 0..7
  const int schunk = (lane & 7) ^ srow;     // pre-swizzled global source chunk
  const uint16_t* ga = A + (size_t)(bm * 256 + w * 32 + srow) * 1024 + schunk * 8;
  const uint16_t* gb = B + (size_t)(bn * 256 + w * 32 + srow) * 1024 + schunk * 8;
  const int sOff = w * 2048;                // wave-uniform LDS base (32 rows x 64)
  const int wm = w >> 2, wn = w & 3;        // 2M x 4N wave grid
  const int fr = lane & 15, quad = lane >> 4;
  f32x4 acc[8][4];
#pragma unroll
  for (int i = 0; i < 8; ++i)
#pragma unroll
    for (int j = 0; j < 4; ++j) acc[i][j] = (f32x4){0.f, 0.f, 0.f, 0.f};

  // per-tile compute from buffer `cur` (24 ds_read_b128 + 64 MFMA / wave)
  auto compute = [&](int cur) {
#pragma unroll
    for (int ko = 0; ko < 2; ++ko) {
      const int kchunk = ((ko * 4 + quad) ^ (fr & 7)) * 8;
      bf16x8 a[8], b[4];
#pragma unroll
      for (int tm = 0; tm < 8; ++tm)
        a[tm] = *(const bf16x8*)&As[cur][(wm * 128 + tm * 16 + fr) * 64 + kchunk];
#pragma unroll
      for (int tn = 0; tn < 4; ++tn)
        b[tn] = *(const bf16x8*)&Bs[cur][(wn * 64 + tn * 16 + fr) * 64 + kchunk];
#pragma unroll
      for (int tm = 0; tm < 8; ++tm)
#pragma unroll
        for (int tn = 0; tn < 4; ++tn)
          acc[tm][tn] = mfma32(a[tm], b[tn], acc[tm][tn]);
    }
  };

  // prologue: stage K-tile 0 into buffer 0 (8 loads/wave)
#pragma unroll
  for (int i = 0; i < 4; ++i) {
    gld16(ga + (size_t)i * 8192, &As[0][sOff + i * 512]);
    gld16(gb + (size_t)i * 8192, &Bs[0][sOff + i * 512]);
  }
  ga += 64; gb += 64;

  for (int kt = 0; kt < 15; ++kt) {
    const int cur = kt & 1;
    // issue prefetch of tile kt+1 into the other buffer (8 loads in flight)
#pragma unroll
    for (int i = 0; i < 4; ++i) {
      gld16(ga + (size_t)i * 8192, &As[cur ^ 1][sOff + i * 512]);
      gld16(gb + (size_t)i * 8192, &Bs[cur ^ 1][sOff + i * 512]);
    }
    ga += 64; gb += 64;
    __builtin_amdgcn_sched_barrier(0);
    asm volatile("s_waitcnt vmcnt(8)" ::: "memory");  // tile kt resident; kt+1 in flight
    __builtin_amdgcn_sched_barrier(0);
    __builtin_amdgcn_s_barrier();                     // raw: no vmcnt drain
    __builtin_amdgcn_sched_barrier(0);
    compute(cur);
    __builtin_amdgcn_sched_barrier(0);
    __builtin_amdgcn_s_barrier();   // all reads of buf[cur] done before kt+2 overwrites
  }
  // epilogue: tile 15 (no prefetch behind it)
  __builtin_amdgcn_sched_barrier(0);
  asm volatile("s_waitcnt vmcnt(0)" ::: "memory");
  __builtin_amdgcn_sched_barrier(0);
  __builtin_amdgcn_s_barrier();
  __builtin_amdgcn_sched_barrier(0);
  compute(1);

  // C/D layout: row = quad*4+r, col = fr (verified m89/m91)
  if (EPI == 0) {
#pragma unroll
    for (int tm = 0; tm < 8; ++tm) {
#pragma unroll
      for (int tn = 0; tn < 4; ++tn) {
        int colg = bn * 256 + wn * 64 + tn * 16 + fr;
#pragma unroll
        for (int r = 0; r < 4; ++r) {
          int l = bm * 256 + wm * 128 + tm * 16 + quad * 4 + r;   // local row
          int t = l >> lgc, nl = l & ((1 << lgc) - 1);
          int n = c0 + nl, b = n >> 10, sp = n & 1023;
          size_t grow = (size_t)b * 16384 + (size_t)t * 1024 + sp;
          F0[grow * 1024 + colg] = acc[tm][tn][r];
        }
      }
    }
  } else {
    // RoPE tables built AFTER the K-loop, reusing As/Bs LDS.
    float* cosT = (float*)As;    // [t][i], t<16, i<32 (512 floats = 2KB)
    float* sinT = (float*)&Bs[0][0];
    __syncthreads();             // all waves done reading As/Bs (full drain ok, once)
    for (int idx = tid; idx < 512; idx += 512) {
      int t = idx >> 5, i = idx & 31;
      float ang = (float)t * expf(-(float)i * 0.28782313662425574f); // 10000^(-i/32)
      cosT[idx] = cosf(ang);
      sinT[idx] = sinf(ang);
    }
    __syncthreads();
    // wave's 64-col span = one (which, head); local row m = nl*16 + t
    const int e0 = bn * 256 + wn * 64;
    const int which = e0 >> 10;
    const int h = (e0 >> 6) & 15;
    const int n_base = bm * 16 + wm * 8;   // local nl base (tm block = one nl)
    if (which == 2) {                      // v: plain scatter to [nl][h][t][d]
#pragma unroll
      for (int tm = 0; tm < 8; ++tm) {
        size_t base = ((size_t)(n_base + tm) * 16 + h) * 1024 + (size_t)(quad * 4) * 64;
#pragma unroll
        for (int tn = 0; tn < 4; ++tn) {
          int d = tn * 16 + fr;
#pragma unroll
          for (int r = 0; r < 4; ++r)
            C2[base + (size_t)r * 64 + d] = f2bf(acc[tm][tn][r]);
        }
      }
    } else {                               // q,k: RoPE (d pairs with d+32)
      uint16_t* dst = (which == 0) ? C0 : C1;
      const float sc = (which == 0) ? 0.125f : 1.0f;  // fold hd^-0.5 into q
#pragma unroll
      for (int tm = 0; tm < 8; ++tm) {
        size_t base0 = ((size_t)(n_base + tm) * 16 + h) * 1024;
#pragma unroll
        for (int tn2 = 0; tn2 < 2; ++tn2) {
          int d1 = tn2 * 16 + fr;          // < 32; pairs with tile tn2+2
#pragma unroll
          for (int r = 0; r < 4; ++r) {
            int t = quad * 4 + r;
            float c = cosT[t * 32 + d1], s = sinT[t * 32 + d1];
            float x1 = acc[tm][tn2][r], x2 = acc[tm][tn2 + 2][r];
            dst[base0 + (size_t)t * 64 + d1]      = f2bf((x1 * c - x2 * s) * sc);
            dst[base0 + (size_t)t * 64 + d1 + 32] = f2bf((x2 * c + x1 * s) * sc);
          }
        }
      }
    }
  }
}

// ---------- 3) causal attention over T=16, one wave per local (nl,h) ----------
// writes o_chunk[t*chunkN + nl][h*64+d] (bf16; reuses the dead xt buffer)
__global__ __launch_bounds__(256)
void attn_chunk(const uint16_t* __restrict__ q, const uint16_t* __restrict__ k,
                const uint16_t* __restrict__ v, uint16_t* __restrict__ out,
                int chunkN) {
  __shared__ float sPT[4][16][17];
  const int wv = threadIdx.x >> 6, lane = threadIdx.x & 63;
  const int pair = blockIdx.x * 4 + wv;     // nl*16 + h
  const int nl = pair >> 4, h = pair & 15;
  const uint16_t* qb = q + (size_t)pair * 1024;   // [t][d] 16x64
  const uint16_t* kb = k + (size_t)pair * 1024;
  const uint16_t* vb = v + (size_t)pair * 1024;
  const int col = lane & 15, quad = lane >> 4;
  const int ro = col * 64 + quad * 8;
  // S^T = K * Q^T : A[m=tk][kd=d] from K rows, B[n=tq][kd=d] from Q rows
  bf16x8 ka0 = *(const bf16x8*)(kb + ro);
  bf16x8 ka1 = *(const bf16x8*)(kb + ro + 32);
  bf16x8 qa0 = *(const bf16x8*)(qb + ro);
  bf16x8 qa1 = *(const bf16x8*)(qb + ro + 32);
  f32x4 s4 = (f32x4){0.f, 0.f, 0.f, 0.f};
  s4 = mfma32(ka0, qa0, s4);
  s4 = mfma32(ka1, qa1, s4);
  // lane holds S^T[tk=quad*4+r][tq=col]; softmax over tk
  float p[4];
  float mx = -3.0e38f;
#pragma unroll
  for (int r = 0; r < 4; ++r) {
    int tk = quad * 4 + r;
    p[r] = (tk <= col) ? s4[r] : -3.0e38f;  // causal mask (finite, no inf-inf)
    mx = fmaxf(mx, p[r]);
  }
  mx = fmaxf(mx, __shfl_xor(mx, 16));
  mx = fmaxf(mx, __shfl_xor(mx, 32));
  float sum = 0.f;
#pragma unroll
  for (int r = 0; r < 4; ++r) {
    p[r] = (p[r] <= -1.0e38f) ? 0.f : expf(p[r] - mx);
    sum += p[r];
  }
  sum += __shfl_xor(sum, 16);
  sum += __shfl_xor(sum, 32);
  const float inv = 1.f / sum;
  // LDS round-trip: P^T(C-layout) -> P(A-layout)
#pragma unroll
  for (int r = 0; r < 4; ++r) sPT[wv][quad * 4 + r][col] = p[r] * inv;
  __syncthreads();
  bf16x8 pa;   // A[m=tq=col][kd=tk=quad*8+j], K-pad quads zeroed
#pragma unroll
  for (int j = 0; j < 8; ++j) {
    float pv = (quad < 2) ? sPT[wv][(quad * 8 + j) & 15][col] : 0.f;
    pa[j] = (__bf16)pv;
  }
  const __bf16* vbf = (const __bf16*)vb;
#pragma unroll
  for (int dt = 0; dt < 4; ++dt) {
    bf16x8 bv;    // B-frag[n=dt*16+col][kd=tk=quad*8+j] = V[tk][d]; pad zeroed
#pragma unroll
    for (int j = 0; j < 8; ++j) {
      int tk = (quad * 8 + j) & 15;
      __bf16 val = vbf[tk * 64 + dt * 16 + col];
      bv[j] = (quad < 2) ? val : (__bf16)0.f;
    }
    f32x4 o = (f32x4){0.f, 0.f, 0.f, 0.f};
    o = mfma32(pa, bv, o);
#pragma unroll
    for (int r = 0; r < 4; ++r) {    // o_chunk[t*chunkN+nl][h*64+d]
      int t = quad * 4 + r;
      out[((size_t)t * chunkN + nl) * 1024 + h * 64 + dt * 16 + col] = f2bf(o[r]);
    }
  }
}

// ---------- launch ----------
extern "C" void kernel_launch(void* const* d_in, const int* in_sizes, int n_in,
                              void* d_out, int out_size, void* d_ws, size_t ws_size,
                              hipStream_t stream) {
  const float* x     = (const float*)d_in[0];
  const float* w_qkv = (const float*)d_in[1];
  const float* w_out = (const float*)d_in[2];
  const float* gamma = (const float*)d_in[3];
  const float* beta  = (const float*)d_in[4];
  float* out = (float*)d_out;

  // ws: [w_qkv_bf 3145728 | w_out_bf 1048576] + per-chunk xt/q/k/v
  uint16_t* wqb = (uint16_t*)d_ws;
  uint16_t* wob = wqb + 3145728;
  uint16_t* base = wob + 1048576;
  const size_t wbytes = 4194304ull * 2;
  size_t avail = (ws_size > wbytes) ? ws_size - wbytes : 0;
  size_t chunkN = 2048;
  while (chunkN > 16 && chunkN * 131072ull > avail) chunkN >>= 1;  // >=16: BM=256 needs 16 nl/block
  int lgc = 31 - __builtin_clz((unsigned)chunkN);
  const int nch = (int)(2048 / chunkN);
  const size_t seg = chunkN * 16384;   // bf16 elems per buffer
  uint16_t* xt = base;                 // xt, later reused as attn output
  uint16_t* qb = xt + seg;
  uint16_t* kb = qb + seg;
  uint16_t* vb = kb + seg;

  conv_w<<<dim3(4096), dim3(256), 0, stream>>>(w_qkv, w_out, wqb);
  for (int c = 0; c < nch; ++c) {
    const int c0 = c * (int)chunkN;
    ln_chunk<<<dim3((uint32_t)chunkN * 4), dim3(256), 0, stream>>>(
        x, gamma, beta, xt, c0);
    gemm_bt<1><<<dim3(12, (uint32_t)chunkN / 16), dim3(512), 0, stream>>>(
        xt, wqb, qb, kb, vb, nullptr, 0, 0);
    attn_chunk<<<dim3((uint32_t)chunkN * 4), dim3(256), 0, stream>>>(
        qb, kb, vb, xt, (int)chunkN);
    gemm_bt<0><<<dim3(4, (uint32_t)chunkN / 16), dim3(512), 0, stream>>>(
        xt, wob, nullptr, nullptr, nullptr, out, c0, lgc);
  }
}